// Round 3
// baseline (327.751 us; speedup 1.0000x reference)
//
#include <hip/hip_runtime.h>
#include <hip/hip_bf16.h>

#define BATCH 64
#define IN_CH 128
#define ILEN  512
#define OLEN  505
#define OCH   128
#define KDIM  1024   // IN_CH * 8
#define NSTEP 32     // K steps of 32

typedef float f32x4 __attribute__((ext_vector_type(4)));
typedef f32x4 f32x4u __attribute__((aligned(4)));   // 4B-aligned vector load (x window is only dword-aligned)
typedef short bf16x8 __attribute__((ext_vector_type(8)));

__device__ __forceinline__ short f2bf(float f) {
  union { __hip_bfloat16 h; short s; } u;
  u.h = __float2bfloat16(f);
  return u.s;
}

// out[b][o][l] = sum_{i,k} x[b][i][l+k] * w[l][o][i*8+k] + bias[o][l]
// Per block (fixed l): GEMM M=64(b) x N=128(o) x K=1024, 8 waves each own 16 o.
// BARRIER-FREE: A fragment for mfma_16x16x32 = x[b][s*4+h][l..l+7] (8 contiguous
// floats) -> direct global->reg. B = w[l][o][s*32+h*8 ..+8] -> direct global->reg.
// No LDS, no __syncthreads, so the w HBM stream is never vmcnt(0)-drained.
template <bool USE_TMP>
__global__ __launch_bounds__(512, 4) void lc1d_main(
    const float* __restrict__ x, const float* __restrict__ w,
    const float* __restrict__ bias, float* __restrict__ outp) {
  const int l    = blockIdx.x;
  const int tid  = threadIdx.x;
  const int lane = tid & 63;
  const int wn   = tid >> 6;        // 0..7 : o 16-slice
  const int r    = lane & 15;
  const int h    = lane >> 4;

  const int o = wn * 16 + r;
  const float* __restrict__ wp =
      w + (size_t)l * (OCH * KDIM) + (size_t)o * KDIM + h * 8;
  const float* __restrict__ xp =
      x + (size_t)r * (IN_CH * ILEN) + (size_t)h * ILEN + l;

  f32x4 acc[4];
#pragma unroll
  for (int m = 0; m < 4; ++m) acc[m] = (f32x4){0.f, 0.f, 0.f, 0.f};

  // ping-pong fragment buffers (named, statically indexed)
  f32x4 a0[4][2], b0[2], a1[4][2], b1[2];

  auto LD = [&](f32x4 (&a)[4][2], f32x4 (&b)[2], int s) {
    const float* xs = xp + (size_t)s * (4 * ILEN);
#pragma unroll
    for (int mt = 0; mt < 4; ++mt) {
      const float* p = xs + (size_t)mt * (16 * IN_CH * ILEN);
      a[mt][0] = *reinterpret_cast<const f32x4u*>(p);
      a[mt][1] = *reinterpret_cast<const f32x4u*>(p + 4);
    }
    const float* q = wp + s * 32;
    b[0] = *reinterpret_cast<const f32x4*>(q);
    b[1] = *reinterpret_cast<const f32x4*>(q + 4);
  };

  auto FMA = [&](f32x4 (&a)[4][2], f32x4 (&b)[2]) {
    bf16x8 bfr;
#pragma unroll
    for (int j = 0; j < 4; ++j) {
      bfr[j]     = f2bf(b[0][j]);
      bfr[4 + j] = f2bf(b[1][j]);
    }
#pragma unroll
    for (int mt = 0; mt < 4; ++mt) {
      bf16x8 afr;
#pragma unroll
      for (int j = 0; j < 4; ++j) {
        afr[j]     = f2bf(a[mt][0][j]);
        afr[4 + j] = f2bf(a[mt][1][j]);
      }
      acc[mt] = __builtin_amdgcn_mfma_f32_16x16x32_bf16(afr, bfr, acc[mt], 0, 0, 0);
    }
  };

  LD(a0, b0, 0);
  LD(a1, b1, 1);
  for (int s = 0; s + 2 < NSTEP; s += 2) {
    FMA(a0, b0);
    LD(a0, b0, s + 2);
    FMA(a1, b1);
    LD(a1, b1, s + 3);
  }
  FMA(a0, b0);
  FMA(a1, b1);

  // C/D layout: col(o)=lane&15, row(b)=(lane>>4)*4+j
  if (USE_TMP) {
    float* t = outp + (size_t)l * (BATCH * OCH) + o;  // tmp[l][b][o], coalesced
#pragma unroll
    for (int mt = 0; mt < 4; ++mt)
#pragma unroll
      for (int j = 0; j < 4; ++j) {
        const int b = mt * 16 + h * 4 + j;
        t[(size_t)b * OCH] = acc[mt][j];
      }
  } else {
    const float bv = bias[o * OLEN + l];
#pragma unroll
    for (int mt = 0; mt < 4; ++mt)
#pragma unroll
      for (int j = 0; j < 4; ++j) {
        const int b = mt * 16 + h * 4 + j;
        outp[(size_t)b * (OCH * OLEN) + (size_t)o * OLEN + l] = acc[mt][j] + bv;
      }
  }
}

// tmp[l][b][o] -> out[b][o][l] (+bias), 64x64 LDS tile transpose
__global__ __launch_bounds__(256) void lc1d_tr(const float* __restrict__ tmp,
                                               const float* __restrict__ bias,
                                               float* __restrict__ out) {
  const int l0  = blockIdx.x * 64;
  const int bo0 = blockIdx.y * 64;
  const int tid = threadIdx.x;
  __shared__ float t[64][65];

  const int boj = tid & 63, lq = tid >> 6;
#pragma unroll
  for (int rr = 0; rr < 16; ++rr) {
    const int li = rr * 4 + lq;
    const int l  = l0 + li;
    if (l < OLEN) t[li][boj] = tmp[(size_t)l * (BATCH * OCH) + bo0 + boj];
  }
  __syncthreads();
  const int lj = tid & 63, bq = tid >> 6;
  const int l  = l0 + lj;
#pragma unroll
  for (int rr = 0; rr < 16; ++rr) {
    const int bl = rr * 4 + bq;
    const int bo = bo0 + bl;
    if (l < OLEN) {
      const int oc = bo & (OCH - 1);
      out[(size_t)bo * OLEN + l] = t[lj][bl] + bias[oc * OLEN + l];
    }
  }
}

extern "C" void kernel_launch(void* const* d_in, const int* in_sizes, int n_in,
                              void* d_out, int out_size, void* d_ws, size_t ws_size,
                              hipStream_t stream) {
  const float* x    = (const float*)d_in[0];
  const float* w    = (const float*)d_in[1];
  const float* bias = (const float*)d_in[2];
  float* out        = (float*)d_out;

  const size_t need = (size_t)OLEN * BATCH * OCH * sizeof(float);  // 16.5 MB
  if (ws_size >= need) {
    float* tmp = (float*)d_ws;
    lc1d_main<true><<<dim3(OLEN), 512, 0, stream>>>(x, w, bias, tmp);
    lc1d_tr<<<dim3(8, 128), 256, 0, stream>>>(tmp, bias, out);
  } else {
    lc1d_main<false><<<dim3(OLEN), 512, 0, stream>>>(x, w, bias, out);
  }
}

// Round 4
// 110.520 us; speedup vs baseline: 2.9655x; 2.9655x over previous
//
#include <hip/hip_runtime.h>
#include <hip/hip_bf16.h>

#define BATCH 64
#define IN_CH 128
#define ILEN  512
#define OLEN  505
#define OCH   128
#define KDIM  1024    // IN_CH * 8
#define BK    64      // K per chunk
#define NCHK  16      // KDIM / BK
#define NWG   (OLEN * 2)

typedef float f32x4  __attribute__((ext_vector_type(4)));
typedef short bf16x8 __attribute__((ext_vector_type(8)));

__device__ __forceinline__ short f2bf(float f) {
  union { __hip_bfloat16 h; short s; } u;
  u.h = __float2bfloat16(f);
  return u.s;
}

// Per block (l, oh): GEMM M=64(b) x N=64(o-half) x K=1024.
// B (weights, the 258MB HBM stream): global_load_lds 16B direct-to-LDS as raw
//   f32, double-buffered, source-swizzled (rule 21) so ds_read_b128 is
//   conflict-free; cvt->bf16 at read time. Issued BEFORE the compute phase so
//   latency hides under MFMA; exactly ONE barrier per chunk.
// A (x window, L2/L3-resident): reg-staged -> bf16 XOR-swizzled LDS, dbuf.
//   A-loads issued before B-stage so the ds_write wait is vmcnt(4), leaving
//   the B stream in flight until the barrier.
template <bool USE_TMP>
__global__ __launch_bounds__(256, 3) void lc1d_main(
    const float* __restrict__ x, const float* __restrict__ w,
    const float* __restrict__ bias, float* __restrict__ outp) {
  // bijective XCD swizzle (m204): each XCD gets a contiguous l-chunk
  {
  }
  const int orig = blockIdx.x;
  const int xcd = orig & 7, idx = orig >> 3;
  const int q = NWG / 8, rr = NWG % 8;
  const int wg = (xcd < rr ? xcd * (q + 1) : rr * (q + 1) + (xcd - rr) * q) + idx;
  const int l  = wg >> 1;
  const int oh = wg & 1;

  const int tid  = threadIdx.x;
  const int lane = tid & 63;
  const int wn   = tid >> 6;        // wave 0..3 -> o 16-slice
  const int r    = lane & 15;
  const int h    = lane >> 4;

  __shared__ float Bs[2][BK * 64];  // 32 KB: row ob (256B), 16B-chunk c' = c ^ swz(ob)
  __shared__ short As[2][BK * 64];  // 16 KB: As[b][kk ^ ((b&7)<<3)]

  f32x4 acc[4];
#pragma unroll
  for (int m = 0; m < 4; ++m) acc[m] = (f32x4){0.f, 0.f, 0.f, 0.f};

  const float* __restrict__ wl =
      w + (size_t)l * (OCH * KDIM) + (size_t)oh * 64 * KDIM;

  // ---- B staging map: thread -> (so = ob&15 base, sc = dest chunk) ----
  const int so  = tid >> 4;          // 0..15 ; ob = it*16 + so
  const int sc  = tid & 15;          // dest 16B-chunk index c'
  const int ssw = ((so & 7) << 1) | ((so >> 3) & 1);  // swz(ob) (it*16 doesn't affect)

  // ---- A staging map ----
  const int kk  = tid & 63;
  const int tb  = tid >> 6;
  const int il  = kk >> 3;
  const int kof = kk & 7;

  float aa[16];

  auto loadA = [&](int kc) {
    const float* xb = x + (size_t)(kc * 8 + il) * ILEN + l + kof;
#pragma unroll
    for (int it = 0; it < 16; ++it)
      aa[it] = xb[(size_t)(it * 4 + tb) * (IN_CH * ILEN)];
  };
  auto writeA = [&](int buf) {
#pragma unroll
    for (int it = 0; it < 16; ++it) {
      const int b = it * 4 + tb;
      As[buf][b * 64 + (kk ^ ((b & 7) << 3))] = f2bf(aa[it]);
    }
  };
  auto stageB = [&](int buf, int kc) {
#pragma unroll
    for (int it = 0; it < 4; ++it) {
      const int ob = it * 16 + so;
      const float* src = wl + (size_t)ob * KDIM + kc * BK + (sc ^ ssw) * 4;
      __builtin_amdgcn_global_load_lds(
          (const __attribute__((address_space(1))) void*)src,
          (__attribute__((address_space(3))) void*)&Bs[buf][ob * 64 + sc * 4],
          16, 0, 0);
    }
  };

  const int rsw = ((r & 7) << 1) | ((r >> 3) & 1);  // swz for my B row
  auto compute = [&](int cur) {
    const int ob = wn * 16 + r;
#pragma unroll
    for (int ks = 0; ks < 2; ++ks) {
      const int c0 = ks * 8 + h * 2;
      const f32x4 blo = *reinterpret_cast<const f32x4*>(
          &Bs[cur][ob * 64 + ((c0) ^ rsw) * 4]);
      const f32x4 bhi = *reinterpret_cast<const f32x4*>(
          &Bs[cur][ob * 64 + ((c0 + 1) ^ rsw) * 4]);
      bf16x8 bfr;
#pragma unroll
      for (int j = 0; j < 4; ++j) {
        bfr[j]     = f2bf(blo[j]);
        bfr[4 + j] = f2bf(bhi[j]);
      }
#pragma unroll
      for (int mt = 0; mt < 4; ++mt) {
        const int b = mt * 16 + r;
        const bf16x8 afr = *reinterpret_cast<const bf16x8*>(
            &As[cur][b * 64 + ((ks * 32 + h * 8) ^ ((b & 7) << 3))]);
        acc[mt] = __builtin_amdgcn_mfma_f32_16x16x32_bf16(afr, bfr, acc[mt], 0, 0, 0);
      }
    }
  };

  // ---- prologue ----
  loadA(0);
  stageB(0, 0);
  writeA(0);          // waits A-loads only (vmcnt(4)); B0 stays in flight
  __syncthreads();    // drains B0

  for (int kc = 0; kc < NCHK; ++kc) {
    const int cur = kc & 1, nxt = cur ^ 1;
    if (kc + 1 < NCHK) {
      loadA(kc + 1);        // x: L2-resident, issued first
      stageB(nxt, kc + 1);  // HBM stream: in flight through the compute phase
    }
    compute(cur);
    if (kc + 1 < NCHK) writeA(nxt);  // vmcnt(4): B still in flight
    __syncthreads();
  }

  // ---- epilogue: C/D layout col(o)=lane&15, row(b)=(lane>>4)*4+j ----
  const int og = oh * 64 + wn * 16 + r;
  if (USE_TMP) {
    float* t = outp + (size_t)l * (BATCH * OCH) + og;  // tmp[l][b][o], coalesced
#pragma unroll
    for (int mt = 0; mt < 4; ++mt)
#pragma unroll
      for (int j = 0; j < 4; ++j) {
        const int b = mt * 16 + h * 4 + j;
        t[(size_t)b * OCH] = acc[mt][j];
      }
  } else {
    const float bv = bias[og * OLEN + l];
#pragma unroll
    for (int mt = 0; mt < 4; ++mt)
#pragma unroll
      for (int j = 0; j < 4; ++j) {
        const int b = mt * 16 + h * 4 + j;
        outp[(size_t)b * (OCH * OLEN) + (size_t)og * OLEN + l] = acc[mt][j] + bv;
      }
  }
}

// tmp[l][b][o] -> out[b][o][l] (+bias), 64x64 LDS tile transpose
__global__ __launch_bounds__(256) void lc1d_tr(const float* __restrict__ tmp,
                                               const float* __restrict__ bias,
                                               float* __restrict__ out) {
  const int l0  = blockIdx.x * 64;
  const int bo0 = blockIdx.y * 64;
  const int tid = threadIdx.x;
  __shared__ float t[64][65];

  const int boj = tid & 63, lq = tid >> 6;
#pragma unroll
  for (int rr = 0; rr < 16; ++rr) {
    const int li = rr * 4 + lq;
    const int l  = l0 + li;
    if (l < OLEN) t[li][boj] = tmp[(size_t)l * (BATCH * OCH) + bo0 + boj];
  }
  __syncthreads();
  const int lj = tid & 63, bq = tid >> 6;
  const int l  = l0 + lj;
#pragma unroll
  for (int rr = 0; rr < 16; ++rr) {
    const int bl = rr * 4 + bq;
    const int bo = bo0 + bl;
    if (l < OLEN) {
      const int oc = bo & (OCH - 1);
      out[(size_t)bo * OLEN + l] = t[lj][bl] + bias[oc * OLEN + l];
    }
  }
}

extern "C" void kernel_launch(void* const* d_in, const int* in_sizes, int n_in,
                              void* d_out, int out_size, void* d_ws, size_t ws_size,
                              hipStream_t stream) {
  const float* x    = (const float*)d_in[0];
  const float* w    = (const float*)d_in[1];
  const float* bias = (const float*)d_in[2];
  float* out        = (float*)d_out;

  const size_t need = (size_t)OLEN * BATCH * OCH * sizeof(float);  // 16.5 MB
  if (ws_size >= need) {
    float* tmp = (float*)d_ws;
    lc1d_main<true><<<dim3(NWG), 256, 0, stream>>>(x, w, bias, tmp);
    lc1d_tr<<<dim3(8, 128), 256, 0, stream>>>(tmp, bias, out);
  } else {
    lc1d_main<false><<<dim3(NWG), 256, 0, stream>>>(x, w, bias, out);
  }
}